// Round 1
// baseline (28.321 us; speedup 1.0000x reference)
//
#include <hip/hip_runtime.h>
#include <math.h>

// YoloLoss: B=512, C=1000, K=8, G=8, channels = 5+C = 1005, plane = G*G = 64
#define NB   512
#define NC   1000
#define NK   8
#define PL   64
#define NCH  1005

// One block per image. 8 waves; lane = grid cell (0..63).
// Waves split the 1000 class channels with stride 8; each lane keeps an
// online logsumexp (m, s) for its cell. Fully coalesced: a wave's 64 lanes
// read one contiguous 256B channel plane per iteration.
__global__ __launch_bounds__(512) void yolo_main(
    const float* __restrict__ out,     // (B, 1005, 64)
    const float* __restrict__ boxes,   // (B, 8, 4)
    const int*   __restrict__ labels,  // (B, 8)   values 1..1000
    const int*   __restrict__ box_xy,  // (B, 8, 2) (x, y)
    const float* __restrict__ obj_t,   // (B, 64)
    float* __restrict__ ws)            // [3 * NB] partials: obj, ce, bb
{
    const int b    = blockIdx.x;
    const int tid  = threadIdx.x;
    const int w    = tid >> 6;
    const int lane = tid & 63;

    const float* plane_base = out + (size_t)b * NCH * PL;
    const float* cls        = plane_base + 5 * PL + lane;

    // ---- online logsumexp over channels w, w+8, ... (branchless) ----
    float m = -1e30f, s = 0.0f;
    #pragma unroll 5
    for (int i = w; i < NC; i += 8) {
        float v  = cls[(size_t)i * PL];
        float nm = fmaxf(m, v);
        s = s * __expf(m - nm) + __expf(v - nm);
        m = nm;
    }

    __shared__ float sm_m[8][64];
    __shared__ float sm_s[8][64];
    __shared__ float lse_sh[64];
    sm_m[w][lane] = m;
    sm_s[w][lane] = s;
    __syncthreads();

    float obj_v = 0.f, ce_v = 0.f, bb_v = 0.f;

    if (w == 0) {
        // merge 8 wave-partials for this cell
        float M = sm_m[0][lane];
        #pragma unroll
        for (int j = 1; j < 8; ++j) M = fmaxf(M, sm_m[j][lane]);
        float S = 0.f;
        #pragma unroll
        for (int j = 0; j < 8; ++j) S += sm_s[j][lane] * __expf(sm_m[j][lane] - M);
        lse_sh[lane] = M + __logf(S);

        // objectness BCE for this cell (channel 0 is post-sigmoid prob)
        float p   = plane_base[lane];
        float t   = obj_t[b * PL + lane];
        float lp  = fmaxf(__logf(p),   -100.0f);
        float l1p = fmaxf(log1pf(-p),  -100.0f);
        obj_v = -(t * lp + (1.0f - t) * l1p);
    }
    __syncthreads();

    if (w == 0 && lane < NK) {
        const int k    = lane;
        const int x    = box_xy[(b * NK + k) * 2 + 0];
        const int y    = box_xy[(b * NK + k) * 2 + 1];
        const int cell = y * 8 + x;
        const int lab  = labels[b * NK + k] - 1;          // 0..999

        float logit = plane_base[(size_t)(5 + lab) * PL + cell];
        ce_v = lse_sh[cell] - logit;

        float acc = 0.f;
        #pragma unroll
        for (int j = 0; j < 4; ++j) {
            float pb = plane_base[(size_t)(1 + j) * PL + cell];
            // target = round(boxes/256*10)/10 ; 10/256 exact in f32, rintf = RNE
            float tv = rintf(boxes[(b * NK + k) * 4 + j] * (10.0f / 256.0f)) / 10.0f;
            float d  = pb - tv;
            acc += d * d;
        }
        bb_v = 0.25f * acc;
    }

    // wave-0 reduces all three partials across its 64 lanes
    if (w == 0) {
        #pragma unroll
        for (int off = 32; off > 0; off >>= 1) {
            obj_v += __shfl_down(obj_v, off);
            ce_v  += __shfl_down(ce_v,  off);
            bb_v  += __shfl_down(bb_v,  off);
        }
        if (lane == 0) {
            ws[b]          = obj_v;
            ws[NB + b]     = ce_v;
            ws[2 * NB + b] = bb_v;
        }
    }
}

// Deterministic final reduction of the 512 per-image partials.
__global__ __launch_bounds__(512) void yolo_finish(
    const float* __restrict__ ws, float* __restrict__ dout)
{
    __shared__ float r0[512], r1[512], r2[512];
    const int tid = threadIdx.x;
    r0[tid] = ws[tid];
    r1[tid] = ws[NB + tid];
    r2[tid] = ws[2 * NB + tid];
    __syncthreads();
    for (int off = 256; off > 0; off >>= 1) {
        if (tid < off) {
            r0[tid] += r0[tid + off];
            r1[tid] += r1[tid + off];
            r2[tid] += r2[tid + off];
        }
        __syncthreads();
    }
    if (tid == 0) {
        float cel_obj   = r0[0] / 32768.0f;   // mean over B*64
        float cel_class = r1[0] / 512.0f;     // sum / B
        float bb_loss   = r2[0] / 512.0f;     // sum / B
        dout[0] = cel_obj + 5.0f * bb_loss + cel_class;  // L1,L2,L3 = 1,5,1
        dout[1] = cel_obj;
        dout[2] = bb_loss;
        dout[3] = cel_class;
    }
}

extern "C" void kernel_launch(void* const* d_in, const int* in_sizes, int n_in,
                              void* d_out, int out_size, void* d_ws, size_t ws_size,
                              hipStream_t stream) {
    const float* outputs = (const float*)d_in[0];
    const float* boxes   = (const float*)d_in[1];
    const int*   labels  = (const int*)d_in[2];
    const int*   box_xy  = (const int*)d_in[3];
    const float* obj_t   = (const float*)d_in[4];
    float* ws   = (float*)d_ws;
    float* dout = (float*)d_out;

    yolo_main<<<NB, 512, 0, stream>>>(outputs, boxes, labels, box_xy, obj_t, ws);
    yolo_finish<<<1, 512, 0, stream>>>(ws, dout);
}